// Round 4
// baseline (395.319 us; speedup 1.0000x reference)
//
#include <hip/hip_runtime.h>
#include <cmath>

// Problem constants (B=1): x (1,4,64,128,128) f32
#define Cc 64
#define Hh 128
#define Ww 128
#define HW_ 16384
#define THW_ 65536
#define CHW_ 1048576
#define NT 27

typedef unsigned short ushort_t;
typedef _Float16 f16x2 __attribute__((ext_vector_type(2)));
typedef _Float16 f16x8 __attribute__((ext_vector_type(8)));
typedef __fp16 fp16x2_alt __attribute__((ext_vector_type(2)));
typedef float floatx4 __attribute__((ext_vector_type(4)));
typedef unsigned uint4v __attribute__((ext_vector_type(4)));

union U32H2 { unsigned u; f16x2 h; };

static __device__ inline ushort_t f2h(float f) {
  union { _Float16 h; ushort_t u; } v;
  v.h = (_Float16)f;
  return v.u;
}

static __device__ inline unsigned pk2(float a) {
  union { fp16x2_alt h; unsigned u; } v;
  v.h = __builtin_amdgcn_cvt_pkrtz(a, a);
  return v.u;
}

// replicate low 16 bits into both halves (weight broadcast for f16x2 math)
static __device__ inline unsigned rep16(unsigned p) {
#if defined(__has_builtin)
#if __has_builtin(__builtin_amdgcn_perm)
  return __builtin_amdgcn_perm(p, p, 0x01000100u);
#else
  return (p & 0xFFFFu) * 0x10001u;
#endif
#else
  return (p & 0xFFFFu) * 0x10001u;
#endif
}

#if defined(__has_builtin)
#if __has_builtin(__builtin_amdgcn_make_buffer_rsrc) && __has_builtin(__builtin_amdgcn_raw_buffer_load_b32) && __has_builtin(__builtin_amdgcn_raw_buffer_load_b128)
#define USE_BUF 1
#endif
#endif
#ifndef USE_BUF
#define USE_BUF 0
#endif

struct XtBuf {
#if USE_BUF
  __amdgpu_buffer_rsrc_t r;
#else
  const char* p;
#endif
};

static __device__ inline XtBuf mkbuf(const ushort_t* xt) {
  XtBuf b;
#if USE_BUF
  b.r = __builtin_amdgcn_make_buffer_rsrc((void*)xt, (short)0, 8388608, 0x00020000);
#else
  b.p = (const char*)xt;
#endif
  return b;
}

static __device__ inline uint4v xload4(const XtBuf& b, unsigned voff) {
#if USE_BUF
  return __builtin_amdgcn_raw_buffer_load_b128(b.r, (int)voff, 0, 0);
#else
  return *(const uint4v*)(b.p + voff);
#endif
}

// ws layout (floats):
//   xt     : [5308416, +2097152)    x -> [t][h][w][c] f16 (4194304 ushorts)
//   wfrag  : [7405568, +55296)      deform weight B-frags, 110592 f16
//   w2frag : [7460864, +82944)      offconv weight B-frags, 165888 f16

// Merged: blocks [0,1024) transpose x -> xt; blocks [1024,1672) weight prep.
__global__ __launch_bounds__(256) void prep_transpose(
    const float* __restrict__ x, ushort_t* __restrict__ xt,
    const float* __restrict__ offset_w,
    const float* __restrict__ weight,
    ushort_t* __restrict__ w2frag,
    ushort_t* __restrict__ wfrag)
{
  __shared__ float tile[64][65];
  if (blockIdx.x < 1024) {
    int b = blockIdx.x;
    int wblk = b & 1;
    int th = b >> 1;
    int h = th & 127;
    int t = th >> 7;
    int w0 = wblk * 64;
    int lane = threadIdx.x & 63;
    int quad = threadIdx.x >> 6;
    #pragma unroll
    for (int cc = 0; cc < 16; ++cc) {
      int c = cc * 4 + quad;
      tile[c][lane] = x[t * CHW_ + c * HW_ + h * Ww + w0 + lane];
    }
    __syncthreads();
    #pragma unroll
    for (int ww = 0; ww < 16; ++ww) {
      int w = ww * 4 + quad;
      xt[(size_t)(t * HW_ + h * Ww + w0 + w) * 64 + lane] = f2h(tile[lane][w]);
    }
  } else {
    int e = (blockIdx.x - 1024) * 256 + threadIdx.x;
    if (e < 165888) {   // offconv: 27 taps x 6 oc-tiles x 2 khalf x 64 lanes x 8
      int j = e & 7, ln = (e >> 3) & 63, kh2 = (e >> 9) & 1, r = e >> 10;
      int ot = r % 6, k = r / 6;
      int oc = ot * 16 + (ln & 15);
      int c  = kh2 * 32 + (ln >> 4) * 8 + j;
      float v = (oc < 81) ? offset_w[(oc * 64 + c) * 27 + k] : 0.f;
      w2frag[e] = f2h(v);
    }
    if (e < 110592) {   // deform: 27 taps x 4 oc-tiles x 2 khalf x 64 lanes x 8
      int j = e & 7, ln = (e >> 3) & 63, kh2 = (e >> 9) & 1, r = e >> 10;
      int ot = r & 3, k = r >> 2;
      int o = ot * 16 + (ln & 15);
      int c = kh2 * 32 + (ln >> 4) * 8 + j;
      wfrag[e] = f2h(weight[(o * 64 + c) * 27 + k]);
    }
  }
}

// One trilinear site: data chunk (uint4v = 8 f16 ch) x packed weight, into
// even/odd f16x2 accumulator chains (bit-identical order to the 107us kernel).
#define SITE(W, D, A0, A1, A2, A3) \
  { U32H2 wu; wu.u = (W); U32H2 q0, q1, q2, q3; \
    q0.u = (D)[0]; q1.u = (D)[1]; q2.u = (D)[2]; q3.u = (D)[3]; \
    A0 += wu.h * q0.h; A1 += wu.h * q1.h; A2 += wu.h * q2.h; A3 += wu.h * q3.h; }

// Fused offset-conv + deformable conv. One block = 2 waves = 32 positions.
// Grid 2048; LDS 16324 -> 16 KB granule -> 10 blocks/CU = 20 waves/CU (the
// round-3 version was 4x256t with 38.9 KB: only 4 blocks/CU resident AND only
// 4 blocks/CU in the grid -- occupancy was the binding limit).
// Meta is packed (site<<16 | rtz-f16 weight) single-buffered LDS, prefetched
// into registers, so consume has no LDS-read latency on the critical path.
__global__ __launch_bounds__(128, 5) void fused(
    const float* __restrict__ x,
    const ushort_t* __restrict__ xt,
    const ushort_t* __restrict__ w2frag,
    const float* __restrict__ ob,
    const ushort_t* __restrict__ wfrag,
    const float* __restrict__ gamma,
    float* __restrict__ out)
{
  __shared__ __align__(16) char lds[16324];
  ushort_t* S = (ushort_t*)lds;               // [32 pos][72 f16] = 4608
  unsigned* pmeta = (unsigned*)(lds + 4608);  // [32 pos][8] u32 = 1024 (packed)
  float* Obuf = (float*)(lds + 5632);         // [81 oc][33] f32 = 10692
  float* Dbuf = (float*)lds;                  // [64 oc][33] f32 (epilogue alias)
  int lane = threadIdx.x & 63;
  int wavei = __builtin_amdgcn_readfirstlane(threadIdx.x >> 6);
  int quad = lane >> 4;
  int m16 = lane & 15;
  int g8 = lane >> 3;
  unsigned coff = (unsigned)((lane & 7) * 16);
  int bid0 = blockIdx.x;
  int p0 = ((bid0 & 7) * 256 + (bid0 >> 3)) * 32;   // XCD swizzle (2048 % 8 == 0)
  int t = p0 >> 14;
  int h = (p0 >> 7) & 127;
  int w0 = p0 & 127;
  XtBuf xb = mkbuf(xt);

  // ---------------- Phase 1: offset conv ----------------
  {
    floatx4 acc[6];
    #pragma unroll
    for (int i = 0; i < 6; ++i) acc[i] = (floatx4){0.f, 0.f, 0.f, 0.f};

    uint4v pd[2];

    auto issue = [&](int k) {
      int kt = k / 9, kh = (k / 3) % 3, kw = k % 3;
      int ts = t + kt - 1, hs = h + kh - 1;
      int tsc = min(max(ts, 0), 3);
      int hsc = min(max(hs, 0), 127);
      int sbase = tsc * HW_ + hsc * Ww;
      #pragma unroll
      for (int b = 0; b < 2; ++b) {
        int prow = wavei * 16 + b * 8 + g8;
        int wc = w0 + prow + kw - 1;
        int wcc = min(max(wc, 0), 127);
        pd[b] = xload4(xb, ((unsigned)(sbase + wcc) << 7) + coff);
      }
    };

    issue(0);
    #pragma unroll 1
    for (int k = 0; k < NT; ++k) {
      int kt = k / 9, kh = (k / 3) % 3, kw = k % 3;
      int ts = t + kt - 1, hs = h + kh - 1;
      bool rowok = ((unsigned)ts < 4u) && ((unsigned)hs < 128u);
      #pragma unroll
      for (int b = 0; b < 2; ++b) {
        int prow = wavei * 16 + b * 8 + g8;
        int wc = w0 + prow + kw - 1;
        bool ok = rowok && ((unsigned)wc < 128u);
        uint4v v = pd[b];
        if (!ok) v = (uint4v){0u, 0u, 0u, 0u};
        *(uint4v*)((char*)S + prow * 144 + coff) = v;
      }
      if (k + 1 < NT) issue(k + 1);
      const ushort_t* srow = S + (wavei * 16 + m16) * 72 + quad * 8;
      f16x8 af0 = *(const f16x8*)srow;
      f16x8 af1 = *(const f16x8*)(srow + 32);
      #pragma unroll
      for (int ot = 0; ot < 6; ++ot) {
        const ushort_t* wb = w2frag + (size_t)((k * 6 + ot) * 2) * 512 + lane * 8;
        f16x8 b0 = *(const f16x8*)(wb);
        f16x8 b1 = *(const f16x8*)(wb + 512);
        acc[ot] = __builtin_amdgcn_mfma_f32_16x16x32_f16(af0, b0, acc[ot], 0, 0, 0);
        acc[ot] = __builtin_amdgcn_mfma_f32_16x16x32_f16(af1, b1, acc[ot], 0, 0, 0);
      }
    }
    // accumulators -> Obuf (+bias); intra-wave (own 16 positions only)
    #pragma unroll
    for (int ot = 0; ot < 6; ++ot) {
      int oc = ot * 16 + m16;
      if (oc < 81) {
        float bv = ob[oc];
        #pragma unroll
        for (int r = 0; r < 4; ++r)
          Obuf[oc * 33 + wavei * 16 + quad * 4 + r] = acc[ot][r] + bv;
      }
    }
  }

  // ---------------- Phase 2: deform ----------------
  floatx4 acc[4];
  #pragma unroll
  for (int i = 0; i < 4; ++i) acc[i] = (floatx4){0.f, 0.f, 0.f, 0.f};

  int pl = wavei * 16 + m16;
  int aq = quad >> 1, bq = quad & 1;
  int rowA = wavei * 16 + g8;
  int rowB = rowA + 8;

  uint4v stA[8], stB[8];
  uint4 pmA0, pmA1, pmB0, pmB1;   // packed meta (site<<16 | f16 weight) in regs

  auto meta = [&](int kk, float dtv, float dhv, float dwv) {
    int kt = kk / 9, kh = (kk / 3) % 3, kw = kk % 3;
    float tf = (float)(t + kt - 1) + dtv;
    float hf = (float)(h + kh - 1) + dhv;
    float wf = (float)(w0 + pl + kw - 1) + dwv;
    float tF = floorf(tf), hF = floorf(hf), wF = floorf(wf);
    float lt = tf - tF, lh_ = hf - hF, lw_ = wf - wF;
    int t0 = (int)tF, h0 = (int)hF, wq_ = (int)wF;
    int ti = t0 + aq;
    float wt_ = (aq ? lt : 1.f - lt) * (((unsigned)ti < 4u) ? 1.f : 0.f);
    int tic = min(max(ti, 0), 3);
    int hi = h0 + bq;
    float wh_ = (bq ? lh_ : 1.f - lh_) * (((unsigned)hi < 128u) ? 1.f : 0.f);
    int hic = min(max(hi, 0), 127);
    int base2 = tic * HW_ + hic * Ww;
    float bw = wt_ * wh_;
    int wi0 = wq_;
    float ww0 = (1.f - lw_) * (((unsigned)wi0 < 128u) ? 1.f : 0.f);
    int wi0c = min(max(wi0, 0), 127);
    int wi1 = wq_ + 1;
    float ww1 = lw_ * (((unsigned)wi1 < 128u) ? 1.f : 0.f);
    int wi1c = min(max(wi1, 0), 127);
    uint2 mp_;
    mp_.x = ((unsigned)(base2 + wi0c) << 16) | (pk2(bw * ww0) & 0xFFFFu);
    mp_.y = ((unsigned)(base2 + wi1c) << 16) | (pk2(bw * ww1) & 0xFFFFu);
    *(uint2*)&pmeta[pl * 8 + quad * 2] = mp_;
  };

  auto mread = [&]() {
    const uint4* mpA = (const uint4*)&pmeta[rowA * 8];
    pmA0 = mpA[0]; pmA1 = mpA[1];
    const uint4* mpB = (const uint4*)&pmeta[rowB * 8];
    pmB0 = mpB[0]; pmB1 = mpB[1];
  };

  // voff from packed word: (site<<7) + coff
  auto vof = [&](unsigned p) -> unsigned {
    return ((p >> 9) & 0xFFFFFF80u) + coff;
  };

  auto issueA = [&]() {
    stA[0] = xload4(xb, vof(pmA0.x));
    stA[1] = xload4(xb, vof(pmA0.y));
    stA[2] = xload4(xb, vof(pmA0.z));
    stA[3] = xload4(xb, vof(pmA0.w));
    stA[4] = xload4(xb, vof(pmA1.x));
    stA[5] = xload4(xb, vof(pmA1.y));
    stA[6] = xload4(xb, vof(pmA1.z));
    stA[7] = xload4(xb, vof(pmA1.w));
  };
  auto issueB = [&]() {
    stB[0] = xload4(xb, vof(pmB0.x));
    stB[1] = xload4(xb, vof(pmB0.y));
    stB[2] = xload4(xb, vof(pmB0.z));
    stB[3] = xload4(xb, vof(pmB0.w));
    stB[4] = xload4(xb, vof(pmB1.x));
    stB[5] = xload4(xb, vof(pmB1.y));
    stB[6] = xload4(xb, vof(pmB1.z));
    stB[7] = xload4(xb, vof(pmB1.w));
  };

  auto consumeA = [&]() {
    U32H2 z; z.u = 0;
    f16x2 e0 = z.h, e1 = z.h, e2 = z.h, e3 = z.h;
    f16x2 o0 = z.h, o1 = z.h, o2 = z.h, o3 = z.h;
    SITE(rep16(pmA0.x), stA[0], e0, e1, e2, e3)
    SITE(rep16(pmA0.y), stA[1], o0, o1, o2, o3)
    SITE(rep16(pmA0.z), stA[2], e0, e1, e2, e3)
    SITE(rep16(pmA0.w), stA[3], o0, o1, o2, o3)
    SITE(rep16(pmA1.x), stA[4], e0, e1, e2, e3)
    SITE(rep16(pmA1.y), stA[5], o0, o1, o2, o3)
    SITE(rep16(pmA1.z), stA[6], e0, e1, e2, e3)
    SITE(rep16(pmA1.w), stA[7], o0, o1, o2, o3)
    U32H2 r0, r1, r2, r3;
    r0.h = e0 + o0; r1.h = e1 + o1; r2.h = e2 + o2; r3.h = e3 + o3;
    uint4v res = {r0.u, r1.u, r2.u, r3.u};
    *(uint4v*)((char*)S + rowA * 144 + coff) = res;
  };
  auto consumeB = [&]() {
    U32H2 z; z.u = 0;
    f16x2 e0 = z.h, e1 = z.h, e2 = z.h, e3 = z.h;
    f16x2 o0 = z.h, o1 = z.h, o2 = z.h, o3 = z.h;
    SITE(rep16(pmB0.x), stB[0], e0, e1, e2, e3)
    SITE(rep16(pmB0.y), stB[1], o0, o1, o2, o3)
    SITE(rep16(pmB0.z), stB[2], e0, e1, e2, e3)
    SITE(rep16(pmB0.w), stB[3], o0, o1, o2, o3)
    SITE(rep16(pmB1.x), stB[4], e0, e1, e2, e3)
    SITE(rep16(pmB1.y), stB[5], o0, o1, o2, o3)
    SITE(rep16(pmB1.z), stB[6], e0, e1, e2, e3)
    SITE(rep16(pmB1.w), stB[7], o0, o1, o2, o3)
    U32H2 r0, r1, r2, r3;
    r0.h = e0 + o0; r1.h = e1 + o1; r2.h = e2 + o2; r3.h = e3 + o3;
    uint4v res = {r0.u, r1.u, r2.u, r3.u};
    *(uint4v*)((char*)S + rowB * 144 + coff) = res;
  };

  // prologue: meta(0) -> regs -> half-A(0) in flight
  {
    float dt0 = Obuf[(0 * NT + 0) * 33 + pl];
    float dh0 = Obuf[(1 * NT + 0) * 33 + pl];
    float dw0 = Obuf[(2 * NT + 0) * 33 + pl];
    meta(0, dt0, dh0, dw0);
  }
  mread();
  issueA();

  #pragma unroll 1
  for (int k = 0; k < NT; ++k) {
    int kn = (k + 1 < NT) ? k + 1 : NT - 1;
    float dt_n = Obuf[(0 * NT + kn) * 33 + pl];
    float dh_n = Obuf[(1 * NT + kn) * 33 + pl];
    float dw_n = Obuf[(2 * NT + kn) * 33 + pl];

    issueB();                                // half-B in flight over consumeA+meta
    __builtin_amdgcn_sched_barrier(0);
    consumeA();                              // S rows [0..8) of wave
    if (k + 1 < NT) meta(kn, dt_n, dh_n, dw_n);  // regs-only consumers below
    consumeB();                              // S rows [8..16) of wave
    if (k + 1 < NT) { mread(); issueA(); }   // half-A(k+1) in flight over MFMAs
    __builtin_amdgcn_sched_barrier(0);

    // --- MFMA
    const ushort_t* srow = S + (wavei * 16 + m16) * 72 + quad * 8;
    f16x8 af0 = *(const f16x8*)srow;
    f16x8 af1 = *(const f16x8*)(srow + 32);
    #pragma unroll
    for (int ot = 0; ot < 4; ++ot) {
      const ushort_t* wb = wfrag + (size_t)((k * 4 + ot) * 2) * 512 + lane * 8;
      f16x8 b0 = *(const f16x8*)(wb);
      f16x8 b1 = *(const f16x8*)(wb + 512);
      acc[ot] = __builtin_amdgcn_mfma_f32_16x16x32_f16(af0, b0, acc[ot], 0, 0, 0);
      acc[ot] = __builtin_amdgcn_mfma_f32_16x16x32_f16(af1, b1, acc[ot], 0, 0, 0);
    }
  }
  __syncthreads();   // S/pmeta/Obuf dead; Dbuf aliases them
  #pragma unroll
  for (int ot = 0; ot < 4; ++ot)
    #pragma unroll
    for (int r = 0; r < 4; ++r)
      Dbuf[(ot * 16 + m16) * 33 + wavei * 16 + quad * 4 + r] = acc[ot][r];
  __syncthreads();
  float g = gamma[0];
  for (int i = threadIdx.x; i < 64 * 32; i += 128) {
    int oc = i >> 5, p = i & 31;
    size_t oi = (size_t)t * CHW_ + (size_t)oc * HW_ + (size_t)h * Ww + w0 + p;
    out[oi] = fmaf(g, Dbuf[oc * 33 + p], x[oi]);
  }
}

extern "C" void kernel_launch(void* const* d_in, const int* in_sizes, int n_in,
                              void* d_out, int out_size, void* d_ws, size_t ws_size,
                              hipStream_t stream) {
  (void)in_sizes; (void)n_in; (void)out_size; (void)ws_size;
  const float* x        = (const float*)d_in[0];
  const float* offset_w = (const float*)d_in[1];
  const float* offset_b = (const float*)d_in[2];
  const float* weight   = (const float*)d_in[3];
  const float* gamma    = (const float*)d_in[4];
  float* out = (float*)d_out;
  float* wsf = (float*)d_ws;
  ushort_t* xt     = (ushort_t*)(wsf + 5308416);        // 4194304 f16
  ushort_t* wfrag  = (ushort_t*)(wsf + 7405568);        // 110592 f16
  ushort_t* w2frag = (ushort_t*)(wsf + 7460864);        // 165888 f16

  hipLaunchKernelGGL(prep_transpose, dim3(1672), dim3(256), 0, stream,
                     x, xt, offset_w, weight, w2frag, wfrag);
  hipLaunchKernelGGL(fused, dim3(2048), dim3(128), 0, stream,
                     x, xt, w2frag, offset_b, wfrag, gamma, out);
}

// Round 5
// 303.439 us; speedup vs baseline: 1.3028x; 1.3028x over previous
//
#include <hip/hip_runtime.h>
#include <cmath>

// Problem constants (B=1): x (1,4,64,128,128) f32
#define Cc 64
#define Hh 128
#define Ww 128
#define HW_ 16384
#define THW_ 65536
#define CHW_ 1048576
#define NT 27

typedef unsigned short ushort_t;
typedef _Float16 f16x2 __attribute__((ext_vector_type(2)));
typedef _Float16 f16x8 __attribute__((ext_vector_type(8)));
typedef __fp16 fp16x2_alt __attribute__((ext_vector_type(2)));
typedef float floatx4 __attribute__((ext_vector_type(4)));
typedef unsigned uint4v __attribute__((ext_vector_type(4)));

union U32H2 { unsigned u; f16x2 h; };

static __device__ inline ushort_t f2h(float f) {
  union { _Float16 h; ushort_t u; } v;
  v.h = (_Float16)f;
  return v.u;
}

static __device__ inline unsigned pk2(float a) {
  union { fp16x2_alt h; unsigned u; } v;
  v.h = __builtin_amdgcn_cvt_pkrtz(a, a);
  return v.u;
}

// replicate low 16 bits into both halves (weight broadcast for f16x2 math)
static __device__ inline unsigned rep16(unsigned p) {
#if defined(__has_builtin)
#if __has_builtin(__builtin_amdgcn_perm)
  return __builtin_amdgcn_perm(p, p, 0x01000100u);
#else
  return (p & 0xFFFFu) * 0x10001u;
#endif
#else
  return (p & 0xFFFFu) * 0x10001u;
#endif
}

#if defined(__has_builtin)
#if __has_builtin(__builtin_amdgcn_make_buffer_rsrc) && __has_builtin(__builtin_amdgcn_raw_buffer_load_b32) && __has_builtin(__builtin_amdgcn_raw_buffer_load_b128)
#define USE_BUF 1
#endif
#endif
#ifndef USE_BUF
#define USE_BUF 0
#endif

struct XtBuf {
#if USE_BUF
  __amdgpu_buffer_rsrc_t r;
#else
  const char* p;
#endif
};

static __device__ inline XtBuf mkbuf(const ushort_t* xt) {
  XtBuf b;
#if USE_BUF
  b.r = __builtin_amdgcn_make_buffer_rsrc((void*)xt, (short)0, 8388608, 0x00020000);
#else
  b.p = (const char*)xt;
#endif
  return b;
}

// NT (non-temporal) gather load: bypass L1 allocation so the per-tap weight
// slices stay L1-resident (gather stream has ~no L1 reuse; weights are read
// 16x per CU per tap).
static __device__ inline uint4v xload4nt(const XtBuf& b, unsigned voff) {
#if USE_BUF
  return __builtin_amdgcn_raw_buffer_load_b128(b.r, (int)voff, 0, 2 /*NT*/);
#else
  return *(const uint4v*)(b.p + voff);
#endif
}

// ws layout (floats):
//   xt     : [5308416, +2097152)    x -> [t][h][w][c] f16 (4194304 ushorts)
//   wfrag  : [7405568, +55296)      deform weight B-frags, 110592 f16
//   w2frag : [7460864, +82944)      offconv weight B-frags, 165888 f16

// Merged: blocks [0,1024) transpose x -> xt; blocks [1024,1672) weight prep.
__global__ __launch_bounds__(256) void prep_transpose(
    const float* __restrict__ x, ushort_t* __restrict__ xt,
    const float* __restrict__ offset_w,
    const float* __restrict__ weight,
    ushort_t* __restrict__ w2frag,
    ushort_t* __restrict__ wfrag)
{
  __shared__ float tile[64][65];
  if (blockIdx.x < 1024) {
    int b = blockIdx.x;
    int wblk = b & 1;
    int th = b >> 1;
    int h = th & 127;
    int t = th >> 7;
    int w0 = wblk * 64;
    int lane = threadIdx.x & 63;
    int quad = threadIdx.x >> 6;
    #pragma unroll
    for (int cc = 0; cc < 16; ++cc) {
      int c = cc * 4 + quad;
      tile[c][lane] = x[t * CHW_ + c * HW_ + h * Ww + w0 + lane];
    }
    __syncthreads();
    #pragma unroll
    for (int ww = 0; ww < 16; ++ww) {
      int w = ww * 4 + quad;
      xt[(size_t)(t * HW_ + h * Ww + w0 + w) * 64 + lane] = f2h(tile[lane][w]);
    }
  } else {
    int e = (blockIdx.x - 1024) * 256 + threadIdx.x;
    if (e < 165888) {   // offconv: 27 taps x 6 oc-tiles x 2 khalf x 64 lanes x 8
      int j = e & 7, ln = (e >> 3) & 63, kh2 = (e >> 9) & 1, r = e >> 10;
      int ot = r % 6, k = r / 6;
      int oc = ot * 16 + (ln & 15);
      int c  = kh2 * 32 + (ln >> 4) * 8 + j;
      float v = (oc < 81) ? offset_w[(oc * 64 + c) * 27 + k] : 0.f;
      w2frag[e] = f2h(v);
    }
    if (e < 110592) {   // deform: 27 taps x 4 oc-tiles x 2 khalf x 64 lanes x 8
      int j = e & 7, ln = (e >> 3) & 63, kh2 = (e >> 9) & 1, r = e >> 10;
      int ot = r & 3, k = r >> 2;
      int o = ot * 16 + (ln & 15);
      int c = kh2 * 32 + (ln >> 4) * 8 + j;
      wfrag[e] = f2h(weight[(o * 64 + c) * 27 + k]);
    }
  }
}

// One trilinear site: data chunk (uint4v = 8 f16 ch) x packed weight, into
// even/odd f16x2 accumulator chains (bit-identical order to the 107us kernel).
#define SITE(W, D, A0, A1, A2, A3) \
  { U32H2 wu; wu.u = (W); U32H2 q0, q1, q2, q3; \
    q0.u = (D)[0]; q1.u = (D)[1]; q2.u = (D)[2]; q3.u = (D)[3]; \
    A0 += wu.h * q0.h; A1 += wu.h * q1.h; A2 += wu.h * q2.h; A3 += wu.h * q3.h; }

// Fused offset-conv + deformable conv. One block = 4 waves = 64 positions
// (round-3 structure: 256 threads, grid 1024, 4 blocks/CU; occupancy is
// structurally capped at 4 waves/SIMD since the phase-2 live set is in the
// 65-128 VGPR tier -- round 4's 5-waves/EU attempt forced spills).
// Round-5 deltas: NT gathers (weights stay L1-resident; kernel is ~85% of an
// L2-BW roofline and weight re-reads are the cuttable term) + packed
// single-buffer meta (validated in round 4).
__global__ __launch_bounds__(256, 4) void fused(
    const float* __restrict__ x,
    const ushort_t* __restrict__ xt,
    const ushort_t* __restrict__ w2frag,
    const float* __restrict__ ob,
    const ushort_t* __restrict__ wfrag,
    const float* __restrict__ gamma,
    float* __restrict__ out)
{
  __shared__ __align__(16) char lds[32324];
  ushort_t* S = (ushort_t*)lds;               // [64 pos][72 f16] = 9216
  unsigned* pmeta = (unsigned*)(lds + 9216);  // [64 pos][8] u32 = 2048 (packed)
  float* Obuf = (float*)(lds + 11264);        // [81 oc][65] f32 = 21060
  float* Dbuf = (float*)lds;                  // [64 oc][65] f32 (epilogue alias)
  int lane = threadIdx.x & 63;
  int wavei = __builtin_amdgcn_readfirstlane(threadIdx.x >> 6);
  int quad = lane >> 4;
  int m16 = lane & 15;
  int g8 = lane >> 3;
  unsigned coff = (unsigned)((lane & 7) * 16);
  int bid0 = blockIdx.x;
  int p0 = ((bid0 & 7) * 128 + (bid0 >> 3)) * 64;   // XCD swizzle (1024 % 8 == 0)
  int t = p0 >> 14;
  int h = (p0 >> 7) & 127;
  int w0 = p0 & 127;
  XtBuf xb = mkbuf(xt);

  // ---------------- Phase 1: offset conv ----------------
  {
    floatx4 acc[6];
    #pragma unroll
    for (int i = 0; i < 6; ++i) acc[i] = (floatx4){0.f, 0.f, 0.f, 0.f};

    uint4v pd[2];

    auto issue = [&](int k) {
      int kt = k / 9, kh = (k / 3) % 3, kw = k % 3;
      int ts = t + kt - 1, hs = h + kh - 1;
      int tsc = min(max(ts, 0), 3);
      int hsc = min(max(hs, 0), 127);
      int sbase = tsc * HW_ + hsc * Ww;
      #pragma unroll
      for (int b = 0; b < 2; ++b) {
        int prow = wavei * 16 + b * 8 + g8;
        int wc = w0 + prow + kw - 1;
        int wcc = min(max(wc, 0), 127);
        pd[b] = xload4nt(xb, ((unsigned)(sbase + wcc) << 7) + coff);
      }
    };

    issue(0);
    #pragma unroll 1
    for (int k = 0; k < NT; ++k) {
      int kt = k / 9, kh = (k / 3) % 3, kw = k % 3;
      int ts = t + kt - 1, hs = h + kh - 1;
      bool rowok = ((unsigned)ts < 4u) && ((unsigned)hs < 128u);
      #pragma unroll
      for (int b = 0; b < 2; ++b) {
        int prow = wavei * 16 + b * 8 + g8;
        int wc = w0 + prow + kw - 1;
        bool ok = rowok && ((unsigned)wc < 128u);
        uint4v v = pd[b];
        if (!ok) v = (uint4v){0u, 0u, 0u, 0u};
        *(uint4v*)((char*)S + prow * 144 + coff) = v;
      }
      if (k + 1 < NT) issue(k + 1);
      const ushort_t* srow = S + (wavei * 16 + m16) * 72 + quad * 8;
      f16x8 af0 = *(const f16x8*)srow;
      f16x8 af1 = *(const f16x8*)(srow + 32);
      #pragma unroll
      for (int ot = 0; ot < 6; ++ot) {
        const ushort_t* wb = w2frag + (size_t)((k * 6 + ot) * 2) * 512 + lane * 8;
        f16x8 b0 = *(const f16x8*)(wb);
        f16x8 b1 = *(const f16x8*)(wb + 512);
        acc[ot] = __builtin_amdgcn_mfma_f32_16x16x32_f16(af0, b0, acc[ot], 0, 0, 0);
        acc[ot] = __builtin_amdgcn_mfma_f32_16x16x32_f16(af1, b1, acc[ot], 0, 0, 0);
      }
    }
    // accumulators -> Obuf (+bias); intra-wave (own 16 positions only)
    #pragma unroll
    for (int ot = 0; ot < 6; ++ot) {
      int oc = ot * 16 + m16;
      if (oc < 81) {
        float bv = ob[oc];
        #pragma unroll
        for (int r = 0; r < 4; ++r)
          Obuf[oc * 65 + wavei * 16 + quad * 4 + r] = acc[ot][r] + bv;
      }
    }
  }

  // ---------------- Phase 2: deform ----------------
  floatx4 acc[4];
  #pragma unroll
  for (int i = 0; i < 4; ++i) acc[i] = (floatx4){0.f, 0.f, 0.f, 0.f};

  int pl = wavei * 16 + m16;
  int aq = quad >> 1, bq = quad & 1;
  int rowA = wavei * 16 + g8;
  int rowB = rowA + 8;

  uint4v stA[8], stB[8];
  uint4 pmA0, pmA1, pmB0, pmB1;   // packed meta (site<<16 | f16 weight) in regs

  auto meta = [&](int kk, float dtv, float dhv, float dwv) {
    int kt = kk / 9, kh = (kk / 3) % 3, kw = kk % 3;
    float tf = (float)(t + kt - 1) + dtv;
    float hf = (float)(h + kh - 1) + dhv;
    float wf = (float)(w0 + pl + kw - 1) + dwv;
    float tF = floorf(tf), hF = floorf(hf), wF = floorf(wf);
    float lt = tf - tF, lh_ = hf - hF, lw_ = wf - wF;
    int t0 = (int)tF, h0 = (int)hF, wq_ = (int)wF;
    int ti = t0 + aq;
    float wt_ = (aq ? lt : 1.f - lt) * (((unsigned)ti < 4u) ? 1.f : 0.f);
    int tic = min(max(ti, 0), 3);
    int hi = h0 + bq;
    float wh_ = (bq ? lh_ : 1.f - lh_) * (((unsigned)hi < 128u) ? 1.f : 0.f);
    int hic = min(max(hi, 0), 127);
    int base2 = tic * HW_ + hic * Ww;
    float bw = wt_ * wh_;
    int wi0 = wq_;
    float ww0 = (1.f - lw_) * (((unsigned)wi0 < 128u) ? 1.f : 0.f);
    int wi0c = min(max(wi0, 0), 127);
    int wi1 = wq_ + 1;
    float ww1 = lw_ * (((unsigned)wi1 < 128u) ? 1.f : 0.f);
    int wi1c = min(max(wi1, 0), 127);
    uint2 mp_;
    mp_.x = ((unsigned)(base2 + wi0c) << 16) | (pk2(bw * ww0) & 0xFFFFu);
    mp_.y = ((unsigned)(base2 + wi1c) << 16) | (pk2(bw * ww1) & 0xFFFFu);
    *(uint2*)&pmeta[pl * 8 + quad * 2] = mp_;
  };

  auto mread = [&]() {
    const uint4* mpA = (const uint4*)&pmeta[rowA * 8];
    pmA0 = mpA[0]; pmA1 = mpA[1];
    const uint4* mpB = (const uint4*)&pmeta[rowB * 8];
    pmB0 = mpB[0]; pmB1 = mpB[1];
  };

  // voff from packed word: (site<<7) + coff
  auto vof = [&](unsigned p) -> unsigned {
    return ((p >> 9) & 0xFFFFFF80u) + coff;
  };

  auto issueA = [&]() {
    stA[0] = xload4nt(xb, vof(pmA0.x));
    stA[1] = xload4nt(xb, vof(pmA0.y));
    stA[2] = xload4nt(xb, vof(pmA0.z));
    stA[3] = xload4nt(xb, vof(pmA0.w));
    stA[4] = xload4nt(xb, vof(pmA1.x));
    stA[5] = xload4nt(xb, vof(pmA1.y));
    stA[6] = xload4nt(xb, vof(pmA1.z));
    stA[7] = xload4nt(xb, vof(pmA1.w));
  };
  auto issueB = [&]() {
    stB[0] = xload4nt(xb, vof(pmB0.x));
    stB[1] = xload4nt(xb, vof(pmB0.y));
    stB[2] = xload4nt(xb, vof(pmB0.z));
    stB[3] = xload4nt(xb, vof(pmB0.w));
    stB[4] = xload4nt(xb, vof(pmB1.x));
    stB[5] = xload4nt(xb, vof(pmB1.y));
    stB[6] = xload4nt(xb, vof(pmB1.z));
    stB[7] = xload4nt(xb, vof(pmB1.w));
  };

  auto consumeA = [&]() {
    U32H2 z; z.u = 0;
    f16x2 e0 = z.h, e1 = z.h, e2 = z.h, e3 = z.h;
    f16x2 o0 = z.h, o1 = z.h, o2 = z.h, o3 = z.h;
    SITE(rep16(pmA0.x), stA[0], e0, e1, e2, e3)
    SITE(rep16(pmA0.y), stA[1], o0, o1, o2, o3)
    SITE(rep16(pmA0.z), stA[2], e0, e1, e2, e3)
    SITE(rep16(pmA0.w), stA[3], o0, o1, o2, o3)
    SITE(rep16(pmA1.x), stA[4], e0, e1, e2, e3)
    SITE(rep16(pmA1.y), stA[5], o0, o1, o2, o3)
    SITE(rep16(pmA1.z), stA[6], e0, e1, e2, e3)
    SITE(rep16(pmA1.w), stA[7], o0, o1, o2, o3)
    U32H2 r0, r1, r2, r3;
    r0.h = e0 + o0; r1.h = e1 + o1; r2.h = e2 + o2; r3.h = e3 + o3;
    uint4v res = {r0.u, r1.u, r2.u, r3.u};
    *(uint4v*)((char*)S + rowA * 144 + coff) = res;
  };
  auto consumeB = [&]() {
    U32H2 z; z.u = 0;
    f16x2 e0 = z.h, e1 = z.h, e2 = z.h, e3 = z.h;
    f16x2 o0 = z.h, o1 = z.h, o2 = z.h, o3 = z.h;
    SITE(rep16(pmB0.x), stB[0], e0, e1, e2, e3)
    SITE(rep16(pmB0.y), stB[1], o0, o1, o2, o3)
    SITE(rep16(pmB0.z), stB[2], e0, e1, e2, e3)
    SITE(rep16(pmB0.w), stB[3], o0, o1, o2, o3)
    SITE(rep16(pmB1.x), stB[4], e0, e1, e2, e3)
    SITE(rep16(pmB1.y), stB[5], o0, o1, o2, o3)
    SITE(rep16(pmB1.z), stB[6], e0, e1, e2, e3)
    SITE(rep16(pmB1.w), stB[7], o0, o1, o2, o3)
    U32H2 r0, r1, r2, r3;
    r0.h = e0 + o0; r1.h = e1 + o1; r2.h = e2 + o2; r3.h = e3 + o3;
    uint4v res = {r0.u, r1.u, r2.u, r3.u};
    *(uint4v*)((char*)S + rowB * 144 + coff) = res;
  };

  // prologue: meta(0) -> regs -> half-A(0) in flight
  {
    float dt0 = Obuf[(0 * NT + 0) * 65 + pl];
    float dh0 = Obuf[(1 * NT + 0) * 65 + pl];
    float dw0 = Obuf[(2 * NT + 0) * 65 + pl];
    meta(0, dt0, dh0, dw0);
  }
  mread();
  issueA();

  #pragma unroll 1
  for (int k = 0; k < NT; ++k) {
    int kn = (k + 1 < NT) ? k + 1 : NT - 1;
    float dt_n = Obuf[(0 * NT + kn) * 65 + pl];
    float dh_n = Obuf[(1 * NT + kn) * 65 + pl];
    float dw_n = Obuf[(2 * NT + kn) * 65 + pl];

    issueB();                                // half-B in flight over consumeA+meta
    __builtin_amdgcn_sched_barrier(0);
    consumeA();                              // S rows [0..8) of wave
    if (k + 1 < NT) meta(kn, dt_n, dh_n, dw_n);  // regs-only consumers below
    consumeB();                              // S rows [8..16) of wave
    if (k + 1 < NT) { mread(); issueA(); }   // half-A(k+1) in flight over MFMAs
    __builtin_amdgcn_sched_barrier(0);

    // --- MFMA
    const ushort_t* srow = S + (wavei * 16 + m16) * 72 + quad * 8;
    f16x8 af0 = *(const f16x8*)srow;
    f16x8 af1 = *(const f16x8*)(srow + 32);
    #pragma unroll
    for (int ot = 0; ot < 4; ++ot) {
      const ushort_t* wb = wfrag + (size_t)((k * 4 + ot) * 2) * 512 + lane * 8;
      f16x8 b0 = *(const f16x8*)(wb);
      f16x8 b1 = *(const f16x8*)(wb + 512);
      acc[ot] = __builtin_amdgcn_mfma_f32_16x16x32_f16(af0, b0, acc[ot], 0, 0, 0);
      acc[ot] = __builtin_amdgcn_mfma_f32_16x16x32_f16(af1, b1, acc[ot], 0, 0, 0);
    }
  }
  __syncthreads();   // S/pmeta/Obuf dead; Dbuf aliases them
  #pragma unroll
  for (int ot = 0; ot < 4; ++ot)
    #pragma unroll
    for (int r = 0; r < 4; ++r)
      Dbuf[(ot * 16 + m16) * 65 + wavei * 16 + quad * 4 + r] = acc[ot][r];
  __syncthreads();
  float g = gamma[0];
  for (int i = threadIdx.x; i < 64 * 64; i += 256) {
    int oc = i >> 6, p = i & 63;
    size_t oi = (size_t)t * CHW_ + (size_t)oc * HW_ + (size_t)h * Ww + w0 + p;
    out[oi] = fmaf(g, Dbuf[oc * 65 + p], x[oi]);
  }
}

extern "C" void kernel_launch(void* const* d_in, const int* in_sizes, int n_in,
                              void* d_out, int out_size, void* d_ws, size_t ws_size,
                              hipStream_t stream) {
  (void)in_sizes; (void)n_in; (void)out_size; (void)ws_size;
  const float* x        = (const float*)d_in[0];
  const float* offset_w = (const float*)d_in[1];
  const float* offset_b = (const float*)d_in[2];
  const float* weight   = (const float*)d_in[3];
  const float* gamma    = (const float*)d_in[4];
  float* out = (float*)d_out;
  float* wsf = (float*)d_ws;
  ushort_t* xt     = (ushort_t*)(wsf + 5308416);        // 4194304 f16
  ushort_t* wfrag  = (ushort_t*)(wsf + 7405568);        // 110592 f16
  ushort_t* w2frag = (ushort_t*)(wsf + 7460864);        // 165888 f16

  hipLaunchKernelGGL(prep_transpose, dim3(1672), dim3(256), 0, stream,
                     x, xt, offset_w, weight, w2frag, wfrag);
  hipLaunchKernelGGL(fused, dim3(1024), dim3(256), 0, stream,
                     x, xt, w2frag, offset_b, wfrag, gamma, out);
}

// Round 7
// 209.374 us; speedup vs baseline: 1.8881x; 1.4493x over previous
//
#include <hip/hip_runtime.h>
#include <cmath>

// Problem constants (B=1): x (1,4,64,128,128) f32
#define Cc 64
#define Hh 128
#define Ww 128
#define HW_ 16384
#define THW_ 65536
#define CHW_ 1048576
#define NT 27

typedef unsigned short ushort_t;
typedef _Float16 f16x2 __attribute__((ext_vector_type(2)));
typedef _Float16 f16x8 __attribute__((ext_vector_type(8)));
typedef __fp16 fp16x2_alt __attribute__((ext_vector_type(2)));
typedef float floatx4 __attribute__((ext_vector_type(4)));
typedef unsigned uint4v __attribute__((ext_vector_type(4)));

union U32H2 { unsigned u; f16x2 h; };

static __device__ inline ushort_t f2h(float f) {
  union { _Float16 h; ushort_t u; } v;
  v.h = (_Float16)f;
  return v.u;
}

static __device__ inline unsigned pk2(float a) {
  union { fp16x2_alt h; unsigned u; } v;
  v.h = __builtin_amdgcn_cvt_pkrtz(a, a);
  return v.u;
}

// replicate low 16 bits into both halves (weight broadcast for f16x2 math)
static __device__ inline unsigned rep16(unsigned p) {
#if defined(__has_builtin)
#if __has_builtin(__builtin_amdgcn_perm)
  return __builtin_amdgcn_perm(p, p, 0x01000100u);
#else
  return (p & 0xFFFFu) * 0x10001u;
#endif
#else
  return (p & 0xFFFFu) * 0x10001u;
#endif
}

#if defined(__has_builtin)
#if __has_builtin(__builtin_amdgcn_make_buffer_rsrc) && __has_builtin(__builtin_amdgcn_raw_buffer_load_b32) && __has_builtin(__builtin_amdgcn_raw_buffer_load_b128)
#define USE_BUF 1
#endif
#endif
#ifndef USE_BUF
#define USE_BUF 0
#endif

struct XtBuf {
#if USE_BUF
  __amdgpu_buffer_rsrc_t r;
#else
  const char* p;
#endif
};

static __device__ inline XtBuf mkbuf(const ushort_t* xt) {
  XtBuf b;
#if USE_BUF
  b.r = __builtin_amdgcn_make_buffer_rsrc((void*)xt, (short)0, 8388608, 0x00020000);
#else
  b.p = (const char*)xt;
#endif
  return b;
}

// plain (cached) gather load -- NT experiment of round 5 regressed: the
// gather stream has real L1/L2 reuse (FETCH 31->92 MB with NT).
static __device__ inline uint4v xload4(const XtBuf& b, unsigned voff) {
#if USE_BUF
  return __builtin_amdgcn_raw_buffer_load_b128(b.r, (int)voff, 0, 0);
#else
  return *(const uint4v*)(b.p + voff);
#endif
}

// ws layout (floats):
//   xt     : [5308416, +2097152)    x -> [t][h][w][c] f16 (4194304 ushorts)
//   wfrag  : [7405568, +55296)      deform weight B-frags, 110592 f16
//   w2frag : [7460864, +82944)      offconv weight B-frags, 165888 f16

// Merged: blocks [0,1024) transpose x -> xt; blocks [1024,1672) weight prep.
__global__ __launch_bounds__(256) void prep_transpose(
    const float* __restrict__ x, ushort_t* __restrict__ xt,
    const float* __restrict__ offset_w,
    const float* __restrict__ weight,
    ushort_t* __restrict__ w2frag,
    ushort_t* __restrict__ wfrag)
{
  __shared__ float tile[64][65];
  if (blockIdx.x < 1024) {
    int b = blockIdx.x;
    int wblk = b & 1;
    int th = b >> 1;
    int h = th & 127;
    int t = th >> 7;
    int w0 = wblk * 64;
    int lane = threadIdx.x & 63;
    int quad = threadIdx.x >> 6;
    #pragma unroll
    for (int cc = 0; cc < 16; ++cc) {
      int c = cc * 4 + quad;
      tile[c][lane] = x[t * CHW_ + c * HW_ + h * Ww + w0 + lane];
    }
    __syncthreads();
    #pragma unroll
    for (int ww = 0; ww < 16; ++ww) {
      int w = ww * 4 + quad;
      xt[(size_t)(t * HW_ + h * Ww + w0 + w) * 64 + lane] = f2h(tile[lane][w]);
    }
  } else {
    int e = (blockIdx.x - 1024) * 256 + threadIdx.x;
    if (e < 165888) {   // offconv: 27 taps x 6 oc-tiles x 2 khalf x 64 lanes x 8
      int j = e & 7, ln = (e >> 3) & 63, kh2 = (e >> 9) & 1, r = e >> 10;
      int ot = r % 6, k = r / 6;
      int oc = ot * 16 + (ln & 15);
      int c  = kh2 * 32 + (ln >> 4) * 8 + j;
      float v = (oc < 81) ? offset_w[(oc * 64 + c) * 27 + k] : 0.f;
      w2frag[e] = f2h(v);
    }
    if (e < 110592) {   // deform: 27 taps x 4 oc-tiles x 2 khalf x 64 lanes x 8
      int j = e & 7, ln = (e >> 3) & 63, kh2 = (e >> 9) & 1, r = e >> 10;
      int ot = r & 3, k = r >> 2;
      int o = ot * 16 + (ln & 15);
      int c = kh2 * 32 + (ln >> 4) * 8 + j;
      wfrag[e] = f2h(weight[(o * 64 + c) * 27 + k]);
    }
  }
}

// One trilinear site: data chunk (uint4v = 8 f16 ch) x packed weight, into
// even/odd f16x2 accumulator chains (bit-identical order to the 107us kernel).
#define SITE(W, D, A0, A1, A2, A3) \
  { U32H2 wu; wu.u = (W); U32H2 q0, q1, q2, q3; \
    q0.u = (D)[0]; q1.u = (D)[1]; q2.u = (D)[2]; q3.u = (D)[3]; \
    A0 += wu.h * q0.h; A1 += wu.h * q1.h; A2 += wu.h * q2.h; A3 += wu.h * q3.h; }

// Fused offset-conv + deformable conv. One block = 4 waves = 64 positions.
// Round-6/7 phase-2 schedule: slot-recycled full-tap pipeline. All 16 gathers
// of tap k+1 are issued inside iteration k, each into the stage slot just
// freed by consuming tap k's same slot (WAR on the register orders it; the
// in-flight window is 8-16 loads; stage stays 64 VGPRs). Load->use distance
// = one full iteration (~2-3x the half-tap schedule). Meta runs a full tap
// ahead in a parity-double-buffered packed pmeta; consume re-reads weights
// from LDS so no second meta register set is needed (live set ~105 VGPR,
// fits the (256,4) 128-reg cap -- round 4 showed exceeding it = scratch
// catastrophe; WRITE_SIZE is the spill canary).
__global__ __launch_bounds__(256, 4) void fused(
    const float* __restrict__ x,
    const ushort_t* __restrict__ xt,
    const ushort_t* __restrict__ w2frag,
    const float* __restrict__ ob,
    const ushort_t* __restrict__ wfrag,
    const float* __restrict__ gamma,
    float* __restrict__ out)
{
  __shared__ __align__(16) char lds[34372];
  ushort_t* S = (ushort_t*)lds;               // [64 pos][72 f16] = 9216
  unsigned* pm0 = (unsigned*)(lds + 9216);    // [64 pos][8] u32 packed (tap even)
  unsigned* pm1 = (unsigned*)(lds + 11264);   // [64 pos][8] u32 packed (tap odd)
  float* Obuf = (float*)(lds + 13312);        // [81 oc][65] f32 = 21060
  float* Dbuf = (float*)lds;                  // [64 oc][65] f32 (epilogue alias)
  int lane = threadIdx.x & 63;
  int wavei = __builtin_amdgcn_readfirstlane(threadIdx.x >> 6);
  int quad = lane >> 4;
  int m16 = lane & 15;
  int g8 = lane >> 3;
  unsigned coff = (unsigned)((lane & 7) * 16);
  int bid0 = blockIdx.x;
  int p0 = ((bid0 & 7) * 128 + (bid0 >> 3)) * 64;   // XCD swizzle (1024 % 8 == 0)
  int t = p0 >> 14;
  int h = (p0 >> 7) & 127;
  int w0 = p0 & 127;
  XtBuf xb = mkbuf(xt);

  // ---------------- Phase 1: offset conv ----------------
  {
    floatx4 acc[6];
    #pragma unroll
    for (int i = 0; i < 6; ++i) acc[i] = (floatx4){0.f, 0.f, 0.f, 0.f};

    uint4v pd[2];

    auto issue = [&](int k) {
      int kt = k / 9, kh = (k / 3) % 3, kw = k % 3;
      int ts = t + kt - 1, hs = h + kh - 1;
      int tsc = min(max(ts, 0), 3);
      int hsc = min(max(hs, 0), 127);
      int sbase = tsc * HW_ + hsc * Ww;
      #pragma unroll
      for (int b = 0; b < 2; ++b) {
        int prow = wavei * 16 + b * 8 + g8;
        int wc = w0 + prow + kw - 1;
        int wcc = min(max(wc, 0), 127);
        pd[b] = xload4(xb, ((unsigned)(sbase + wcc) << 7) + coff);
      }
    };

    issue(0);
    #pragma unroll 1
    for (int k = 0; k < NT; ++k) {
      int kt = k / 9, kh = (k / 3) % 3, kw = k % 3;
      int ts = t + kt - 1, hs = h + kh - 1;
      bool rowok = ((unsigned)ts < 4u) && ((unsigned)hs < 128u);
      #pragma unroll
      for (int b = 0; b < 2; ++b) {
        int prow = wavei * 16 + b * 8 + g8;
        int wc = w0 + prow + kw - 1;
        bool ok = rowok && ((unsigned)wc < 128u);
        uint4v v = pd[b];
        if (!ok) v = (uint4v){0u, 0u, 0u, 0u};
        *(uint4v*)((char*)S + prow * 144 + coff) = v;
      }
      if (k + 1 < NT) issue(k + 1);
      const ushort_t* srow = S + (wavei * 16 + m16) * 72 + quad * 8;
      f16x8 af0 = *(const f16x8*)srow;
      f16x8 af1 = *(const f16x8*)(srow + 32);
      #pragma unroll
      for (int ot = 0; ot < 6; ++ot) {
        const ushort_t* wb = w2frag + (size_t)((k * 6 + ot) * 2) * 512 + lane * 8;
        f16x8 b0 = *(const f16x8*)(wb);
        f16x8 b1 = *(const f16x8*)(wb + 512);
        acc[ot] = __builtin_amdgcn_mfma_f32_16x16x32_f16(af0, b0, acc[ot], 0, 0, 0);
        acc[ot] = __builtin_amdgcn_mfma_f32_16x16x32_f16(af1, b1, acc[ot], 0, 0, 0);
      }
    }
    // accumulators -> Obuf (+bias); intra-wave (own 16 positions only)
    #pragma unroll
    for (int ot = 0; ot < 6; ++ot) {
      int oc = ot * 16 + m16;
      if (oc < 81) {
        float bv = ob[oc];
        #pragma unroll
        for (int r = 0; r < 4; ++r)
          Obuf[oc * 65 + wavei * 16 + quad * 4 + r] = acc[ot][r] + bv;
      }
    }
  }

  // ---------------- Phase 2: deform ----------------
  floatx4 acc[4];
  #pragma unroll
  for (int i = 0; i < 4; ++i) acc[i] = (floatx4){0.f, 0.f, 0.f, 0.f};

  int pl = wavei * 16 + m16;
  int aq = quad >> 1, bq = quad & 1;
  int rowA = wavei * 16 + g8;
  int rowB = rowA + 8;

  uint4v stage[16];   // slot-recycled register staging (64 VGPRs)

  auto meta = [&](int kk, float dtv, float dhv, float dwv) {
    unsigned* pm = (kk & 1) ? pm1 : pm0;
    int kt = kk / 9, kh = (kk / 3) % 3, kw = kk % 3;
    float tf = (float)(t + kt - 1) + dtv;
    float hf = (float)(h + kh - 1) + dhv;
    float wf = (float)(w0 + pl + kw - 1) + dwv;
    float tF = floorf(tf), hF = floorf(hf), wF = floorf(wf);
    float lt = tf - tF, lh_ = hf - hF, lw_ = wf - wF;
    int t0 = (int)tF, h0 = (int)hF, wq_ = (int)wF;
    int ti = t0 + aq;
    float wt_ = (aq ? lt : 1.f - lt) * (((unsigned)ti < 4u) ? 1.f : 0.f);
    int tic = min(max(ti, 0), 3);
    int hi = h0 + bq;
    float wh_ = (bq ? lh_ : 1.f - lh_) * (((unsigned)hi < 128u) ? 1.f : 0.f);
    int hic = min(max(hi, 0), 127);
    int base2 = tic * HW_ + hic * Ww;
    float bw = wt_ * wh_;
    int wi0 = wq_;
    float ww0 = (1.f - lw_) * (((unsigned)wi0 < 128u) ? 1.f : 0.f);
    int wi0c = min(max(wi0, 0), 127);
    int wi1 = wq_ + 1;
    float ww1 = lw_ * (((unsigned)wi1 < 128u) ? 1.f : 0.f);
    int wi1c = min(max(wi1, 0), 127);
    uint2 mp_;
    mp_.x = ((unsigned)(base2 + wi0c) << 16) | (pk2(bw * ww0) & 0xFFFFu);
    mp_.y = ((unsigned)(base2 + wi1c) << 16) | (pk2(bw * ww1) & 0xFFFFu);
    *(uint2*)&pm[pl * 8 + quad * 2] = mp_;
  };

  // voff from packed word: (site<<7) + coff
  auto vof = [&](unsigned p) -> unsigned {
    return ((p >> 9) & 0xFFFFFF80u) + coff;
  };

  // consume tap kk's half (stage base bi: 0=A rows, 8=B rows), weights
  // re-read from pmeta[kk&1]; then issue tap kk+1's same half into the
  // freed slots (sites from pmeta[(kk+1)&1]).
  auto halfA = [&](int kk, bool more) {
    const unsigned* pmc = (kk & 1) ? pm1 : pm0;
    const uint4* wp = (const uint4*)&pmc[rowA * 8];
    uint4 w03 = wp[0], w47 = wp[1];
    U32H2 z; z.u = 0;
    f16x2 e0 = z.h, e1 = z.h, e2 = z.h, e3 = z.h;
    f16x2 o0 = z.h, o1 = z.h, o2 = z.h, o3 = z.h;
    SITE(rep16(w03.x), stage[0], e0, e1, e2, e3)
    SITE(rep16(w03.y), stage[1], o0, o1, o2, o3)
    SITE(rep16(w03.z), stage[2], e0, e1, e2, e3)
    SITE(rep16(w03.w), stage[3], o0, o1, o2, o3)
    SITE(rep16(w47.x), stage[4], e0, e1, e2, e3)
    SITE(rep16(w47.y), stage[5], o0, o1, o2, o3)
    SITE(rep16(w47.z), stage[6], e0, e1, e2, e3)
    SITE(rep16(w47.w), stage[7], o0, o1, o2, o3)
    U32H2 r0, r1, r2, r3;
    r0.h = e0 + o0; r1.h = e1 + o1; r2.h = e2 + o2; r3.h = e3 + o3;
    uint4v res = {r0.u, r1.u, r2.u, r3.u};
    *(uint4v*)((char*)S + rowA * 144 + coff) = res;
    if (more) {
      const unsigned* pmn = (kk & 1) ? pm0 : pm1;
      const uint4* sp = (const uint4*)&pmn[rowA * 8];
      uint4 s0 = sp[0], s1 = sp[1];
      stage[0] = xload4(xb, vof(s0.x));
      stage[1] = xload4(xb, vof(s0.y));
      stage[2] = xload4(xb, vof(s0.z));
      stage[3] = xload4(xb, vof(s0.w));
      stage[4] = xload4(xb, vof(s1.x));
      stage[5] = xload4(xb, vof(s1.y));
      stage[6] = xload4(xb, vof(s1.z));
      stage[7] = xload4(xb, vof(s1.w));
    }
  };
  auto halfB = [&](int kk, bool more) {
    const unsigned* pmc = (kk & 1) ? pm1 : pm0;
    const uint4* wp = (const uint4*)&pmc[rowB * 8];
    uint4 w03 = wp[0], w47 = wp[1];
    U32H2 z; z.u = 0;
    f16x2 e0 = z.h, e1 = z.h, e2 = z.h, e3 = z.h;
    f16x2 o0 = z.h, o1 = z.h, o2 = z.h, o3 = z.h;
    SITE(rep16(w03.x), stage[8],  e0, e1, e2, e3)
    SITE(rep16(w03.y), stage[9],  o0, o1, o2, o3)
    SITE(rep16(w03.z), stage[10], e0, e1, e2, e3)
    SITE(rep16(w03.w), stage[11], o0, o1, o2, o3)
    SITE(rep16(w47.x), stage[12], e0, e1, e2, e3)
    SITE(rep16(w47.y), stage[13], o0, o1, o2, o3)
    SITE(rep16(w47.z), stage[14], e0, e1, e2, e3)
    SITE(rep16(w47.w), stage[15], o0, o1, o2, o3)
    U32H2 r0, r1, r2, r3;
    r0.h = e0 + o0; r1.h = e1 + o1; r2.h = e2 + o2; r3.h = e3 + o3;
    uint4v res = {r0.u, r1.u, r2.u, r3.u};
    *(uint4v*)((char*)S + rowB * 144 + coff) = res;
    if (more) {
      const unsigned* pmn = (kk & 1) ? pm0 : pm1;
      const uint4* sp = (const uint4*)&pmn[rowB * 8];
      uint4 s0 = sp[0], s1 = sp[1];
      stage[8]  = xload4(xb, vof(s0.x));
      stage[9]  = xload4(xb, vof(s0.y));
      stage[10] = xload4(xb, vof(s0.z));
      stage[11] = xload4(xb, vof(s0.w));
      stage[12] = xload4(xb, vof(s1.x));
      stage[13] = xload4(xb, vof(s1.y));
      stage[14] = xload4(xb, vof(s1.z));
      stage[15] = xload4(xb, vof(s1.w));
    }
  };

  // prologue: meta(0) -> issue tap 0 (both halves)
  {
    float dt0 = Obuf[(0 * NT + 0) * 65 + pl];
    float dh0 = Obuf[(1 * NT + 0) * 65 + pl];
    float dw0 = Obuf[(2 * NT + 0) * 65 + pl];
    meta(0, dt0, dh0, dw0);
  }
  {
    const uint4* spA = (const uint4*)&pm0[rowA * 8];
    uint4 a0 = spA[0], a1 = spA[1];
    stage[0] = xload4(xb, vof(a0.x));
    stage[1] = xload4(xb, vof(a0.y));
    stage[2] = xload4(xb, vof(a0.z));
    stage[3] = xload4(xb, vof(a0.w));
    stage[4] = xload4(xb, vof(a1.x));
    stage[5] = xload4(xb, vof(a1.y));
    stage[6] = xload4(xb, vof(a1.z));
    stage[7] = xload4(xb, vof(a1.w));
    const uint4* spB = (const uint4*)&pm0[rowB * 8];
    uint4 b0 = spB[0], b1 = spB[1];
    stage[8]  = xload4(xb, vof(b0.x));
    stage[9]  = xload4(xb, vof(b0.y));
    stage[10] = xload4(xb, vof(b0.z));
    stage[11] = xload4(xb, vof(b0.w));
    stage[12] = xload4(xb, vof(b1.x));
    stage[13] = xload4(xb, vof(b1.y));
    stage[14] = xload4(xb, vof(b1.z));
    stage[15] = xload4(xb, vof(b1.w));
  }

  #pragma unroll 1
  for (int k = 0; k < NT; ++k) {
    bool more = (k + 1 < NT);
    // meta for tap k+1 (full tap ahead) -> pmeta[(k+1)&1]
    if (more) {
      float dt_n = Obuf[(0 * NT + (k + 1)) * 65 + pl];
      float dh_n = Obuf[(1 * NT + (k + 1)) * 65 + pl];
      float dw_n = Obuf[(2 * NT + (k + 1)) * 65 + pl];
      meta(k + 1, dt_n, dh_n, dw_n);
    }
    __builtin_amdgcn_sched_barrier(0);
    halfA(k, more);    // consume tap k rows A (vmcnt(8): B still in flight), reissue
    __builtin_amdgcn_sched_barrier(0);
    halfB(k, more);    // consume tap k rows B (vmcnt(8): A' in flight), reissue
    __builtin_amdgcn_sched_barrier(0);

    // --- MFMA tap k
    const ushort_t* srow = S + (wavei * 16 + m16) * 72 + quad * 8;
    f16x8 af0 = *(const f16x8*)srow;
    f16x8 af1 = *(const f16x8*)(srow + 32);
    #pragma unroll
    for (int ot = 0; ot < 4; ++ot) {
      const ushort_t* wb = wfrag + (size_t)((k * 4 + ot) * 2) * 512 + lane * 8;
      f16x8 b0 = *(const f16x8*)(wb);
      f16x8 b1 = *(const f16x8*)(wb + 512);
      acc[ot] = __builtin_amdgcn_mfma_f32_16x16x32_f16(af0, b0, acc[ot], 0, 0, 0);
      acc[ot] = __builtin_amdgcn_mfma_f32_16x16x32_f16(af1, b1, acc[ot], 0, 0, 0);
    }
  }
  __syncthreads();   // S/pmeta/Obuf dead; Dbuf aliases them
  #pragma unroll
  for (int ot = 0; ot < 4; ++ot)
    #pragma unroll
    for (int r = 0; r < 4; ++r)
      Dbuf[(ot * 16 + m16) * 65 + wavei * 16 + quad * 4 + r] = acc[ot][r];
  __syncthreads();
  float g = gamma[0];
  for (int i = threadIdx.x; i < 64 * 64; i += 256) {
    int oc = i >> 6, p = i & 63;
    size_t oi = (size_t)t * CHW_ + (size_t)oc * HW_ + (size_t)h * Ww + w0 + p;
    out[oi] = fmaf(g, Dbuf[oc * 65 + p], x[oi]);
  }
}

extern "C" void kernel_launch(void* const* d_in, const int* in_sizes, int n_in,
                              void* d_out, int out_size, void* d_ws, size_t ws_size,
                              hipStream_t stream) {
  (void)in_sizes; (void)n_in; (void)out_size; (void)ws_size;
  const float* x        = (const float*)d_in[0];
  const float* offset_w = (const float*)d_in[1];
  const float* offset_b = (const float*)d_in[2];
  const float* weight   = (const float*)d_in[3];
  const float* gamma    = (const float*)d_in[4];
  float* out = (float*)d_out;
  float* wsf = (float*)d_ws;
  ushort_t* xt     = (ushort_t*)(wsf + 5308416);        // 4194304 f16
  ushort_t* wfrag  = (ushort_t*)(wsf + 7405568);        // 110592 f16
  ushort_t* w2frag = (ushort_t*)(wsf + 7460864);        // 165888 f16

  hipLaunchKernelGGL(prep_transpose, dim3(1672), dim3(256), 0, stream,
                     x, xt, offset_w, weight, w2frag, wfrag);
  hipLaunchKernelGGL(fused, dim3(1024), dim3(256), 0, stream,
                     x, xt, w2frag, offset_b, wfrag, gamma, out);
}